// Round 1
// baseline (56.717 us; speedup 1.0000x reference)
//
#include <hip/hip_runtime.h>

// Problem dims (fixed by setup_inputs): B=32, C=3, IMG=256, N=IMG^2=65536,
// K = C*N/4 = 49152, JMAX = K/C = 16384.
#define NTOT 65536
#define CCH 3
#define BB 32
#define KK 49152
#define JMAXV 16384
#define SCALE (1.0f / 256.0f)

// Build inverse permutation: inv[n] = j if perm[j]==n and j<JMAX else -1.
__global__ __launch_bounds__(256) void build_inv_k(const int* __restrict__ perm,
                                                   int* __restrict__ inv) {
    int j = blockIdx.x * 256 + threadIdx.x;   // grid covers exactly NTOT
    int n = perm[j];
    inv[n] = (j < JMAXV) ? j : -1;
}

__device__ __forceinline__ void bfly(float& a, float& b) {
    float s = a + b;
    float d = a - b;
    a = s; b = d;
}

// Pass 1: 256-point FWHT over the LOW 8 bits of n (contiguous segments).
// One wave per 256-float segment; lane holds lo = lane*4 + r (r=0..3).
// lo bits 0,1 = r (in-register), lo bits 2..7 = lane bits 0..5 (shfl_xor).
__global__ __launch_bounds__(256) void fwht_lo_k(const float* __restrict__ src,
                                                 float* __restrict__ dst) {
    int gid  = blockIdx.x * 256 + threadIdx.x;
    int wave = gid >> 6;
    int lane = gid & 63;
    size_t base = (size_t)wave * 256 + lane * 4;
    float4 v = *reinterpret_cast<const float4*>(src + base);
    float w0 = v.x, w1 = v.y, w2 = v.z, w3 = v.w;
    bfly(w0, w1); bfly(w2, w3);   // lo bit 0
    bfly(w0, w2); bfly(w1, w3);   // lo bit 1
#pragma unroll
    for (int m = 1; m <= 32; m <<= 1) {   // lo bits 2..7
        float p0 = __shfl_xor(w0, m);
        float p1 = __shfl_xor(w1, m);
        float p2 = __shfl_xor(w2, m);
        float p3 = __shfl_xor(w3, m);
        if (lane & m) { w0 = p0 - w0; w1 = p1 - w1; w2 = p2 - w2; w3 = p3 - w3; }
        else          { w0 = w0 + p0; w1 = w1 + p1; w2 = w2 + p2; w3 = w3 + p3; }
    }
    float4 o; o.x = w0; o.y = w1; o.z = w2; o.w = w3;
    *reinterpret_cast<float4*>(dst + base) = o;
}

// Pass 2: 256-point FWHT over the HIGH 8 bits (stride-256 columns), then
// scale 1/256 and scatter to out via inv + singulars.
// Block = 256 threads handles a tile of 16 lo-columns x 256 hi for one
// (b,c) row. Tile staged in LDS with stride 17 (odd -> conflict-free
// column reads). Wave w handles lo-columns w*4..w*4+3; lane holds
// hi = r*64 + lane (r=0..3): hi bits 0..5 = lane (shfl), bits 6,7 = r.
__global__ __launch_bounds__(256) void fwht_hi_scatter_k(
        const float* __restrict__ mid, const int* __restrict__ inv,
        const float* __restrict__ sing, float* __restrict__ out) {
    __shared__ float lds[256 * 17];
    int tile  = blockIdx.x;      // 0 .. B*C*16 - 1
    int row   = tile >> 4;       // b*C + c
    int lo0   = (tile & 15) * 16;
    const float* base = mid + (size_t)row * NTOT;

    int t = threadIdx.x;
    int q = t & 3;               // which float4 within 16 lo
    int hib = t >> 2;            // 0..63
#pragma unroll
    for (int i = 0; i < 4; ++i) {
        int hi = hib + i * 64;
        float4 g = *reinterpret_cast<const float4*>(base + (size_t)hi * 256 + lo0 + q * 4);
        float* p = &lds[hi * 17 + q * 4];
        p[0] = g.x; p[1] = g.y; p[2] = g.z; p[3] = g.w;
    }
    __syncthreads();

    int lane = t & 63;
    int wid  = t >> 6;
    int b = row / CCH;
    int c = row % CCH;

#pragma unroll
    for (int cc = 0; cc < 4; ++cc) {
        int lol = wid * 4 + cc;
        float v[4];
#pragma unroll
        for (int r = 0; r < 4; ++r)
            v[r] = lds[(r * 64 + lane) * 17 + lol];

#pragma unroll
        for (int m = 1; m <= 32; m <<= 1) {   // hi bits 0..5
            float p0 = __shfl_xor(v[0], m);
            float p1 = __shfl_xor(v[1], m);
            float p2 = __shfl_xor(v[2], m);
            float p3 = __shfl_xor(v[3], m);
            if (lane & m) { v[0] = p0 - v[0]; v[1] = p1 - v[1]; v[2] = p2 - v[2]; v[3] = p3 - v[3]; }
            else          { v[0] = v[0] + p0; v[1] = v[1] + p1; v[2] = v[2] + p2; v[3] = v[3] + p3; }
        }
        bfly(v[0], v[1]); bfly(v[2], v[3]);   // hi bit 6 (r bit 0)
        bfly(v[0], v[2]); bfly(v[1], v[3]);   // hi bit 7 (r bit 1)

        int lo = lo0 + lol;
#pragma unroll
        for (int r = 0; r < 4; ++r) {
            int hi = r * 64 + lane;
            int n  = hi * 256 + lo;
            int j  = inv[n];
            if (j >= 0) {
                float val = v[r] * SCALE;
                out[(size_t)b * KK + j * CCH + c] = sing[j * CCH + c] * val;
            }
        }
    }
}

extern "C" void kernel_launch(void* const* d_in, const int* in_sizes, int n_in,
                              void* d_out, int out_size, void* d_ws, size_t ws_size,
                              hipStream_t stream) {
    const float* vec  = (const float*)d_in[0];
    const float* sing = (const float*)d_in[1];
    const int*   perm = (const int*)d_in[2];
    float* out = (float*)d_out;

    int*   inv = (int*)d_ws;                                  // 65536 ints = 256 KB
    float* mid = (float*)((char*)d_ws + NTOT * sizeof(int));  // B*C*N floats = 24 MB

    // inv build: 256 blocks x 256 threads = exactly NTOT
    build_inv_k<<<NTOT / 256, 256, 0, stream>>>(perm, inv);

    // pass 1: one wave per 256-float segment; segments = B*C*256 = 24576
    int segs = BB * CCH * (NTOT / 256);
    fwht_lo_k<<<segs / 4, 256, 0, stream>>>(vec, mid);

    // pass 2: one block per (row, 16-lo-column group); B*C*16 = 1536 blocks
    fwht_hi_scatter_k<<<BB * CCH * 16, 256, 0, stream>>>(mid, inv, sing, out);
}

// Round 2
// 41.293 us; speedup vs baseline: 1.3735x; 1.3735x over previous
//
#include <hip/hip_runtime.h>

// Problem dims (fixed by setup_inputs): B=32, C=3, IMG=256, N=IMG^2=65536,
// K = C*N/4 = 49152, JMAX = K/C = 16384.
#define NTOT 65536
#define CCH 3
#define BB 32
#define KK 49152
#define JMAXV 16384

struct F3 { float x, y, z; };

// Build tables over j (coalesced reads, scattered small writes):
//   jtab[n] = j if perm[j]==n and j<JMAX else -1
//   sp[3n..3n+2] = sing[3j..3j+2] / 256   (scale folded in)
__global__ __launch_bounds__(256) void build_tabs_k(const int* __restrict__ perm,
                                                    const float* __restrict__ sing,
                                                    int* __restrict__ jtab,
                                                    float* __restrict__ sp) {
    int j = blockIdx.x * 256 + threadIdx.x;   // grid covers exactly NTOT
    int n = perm[j];
    if (j < JMAXV) {
        jtab[n] = j;
        F3 s = *reinterpret_cast<const F3*>(sing + 3 * j);
        F3 o;
        o.x = s.x * (1.0f / 256.0f);
        o.y = s.y * (1.0f / 256.0f);
        o.z = s.z * (1.0f / 256.0f);
        *reinterpret_cast<F3*>(sp + 3 * n) = o;
    } else {
        jtab[n] = -1;
    }
}

__device__ __forceinline__ void bfly(float& a, float& b) {
    float s = a + b;
    float d = a - b;
    a = s; b = d;
}

// Pass 1: 256-point FWHT over the LOW 8 bits of n (contiguous segments).
// One wave per 256-float segment; lane holds lo = lane*4 + r (r=0..3).
__global__ __launch_bounds__(256) void fwht_lo_k(const float* __restrict__ src,
                                                 float* __restrict__ dst) {
    int gid  = blockIdx.x * 256 + threadIdx.x;
    int wave = gid >> 6;
    int lane = gid & 63;
    size_t base = (size_t)wave * 256 + lane * 4;
    float4 v = *reinterpret_cast<const float4*>(src + base);
    float w0 = v.x, w1 = v.y, w2 = v.z, w3 = v.w;
    bfly(w0, w1); bfly(w2, w3);   // lo bit 0
    bfly(w0, w2); bfly(w1, w3);   // lo bit 1
#pragma unroll
    for (int m = 1; m <= 32; m <<= 1) {   // lo bits 2..7
        float p0 = __shfl_xor(w0, m);
        float p1 = __shfl_xor(w1, m);
        float p2 = __shfl_xor(w2, m);
        float p3 = __shfl_xor(w3, m);
        if (lane & m) { w0 = p0 - w0; w1 = p1 - w1; w2 = p2 - w2; w3 = p3 - w3; }
        else          { w0 = w0 + p0; w1 = w1 + p1; w2 = w2 + p2; w3 = w3 + p3; }
    }
    float4 o; o.x = w0; o.y = w1; o.z = w2; o.w = w3;
    *reinterpret_cast<float4*>(dst + base) = o;
}

// Pass 2: 256-point FWHT over the HIGH 8 bits for ALL 3 channels of one
// (b, 16-lo-column) tile, then fused scatter:
//   out[b][3j+c] = sp[3n+c] * y_c[n]   where j = jtab[n] >= 0
// Block = 512 threads (8 waves). LDS tile stride-17 for column reads;
// results transposed back at stride-49 so the scatter loop is n-contiguous.
__global__ __launch_bounds__(512) void fwht_hi_scatter_k(
        const float* __restrict__ mid, const int* __restrict__ jtab,
        const float* __restrict__ sp, float* __restrict__ out) {
    __shared__ float lds[13056];   // max(768*17, 256*49) floats = 52224 B
    int tile = blockIdx.x;         // 0 .. B*16 - 1
    int b    = tile >> 4;
    int lo0  = (tile & 15) * 16;
    const float* base = mid + (size_t)b * (CCH * NTOT);
    int t = threadIdx.x;

    // Load 3 channels x 256 hi x 16 lo = 3072 float4 into LDS (stride 17).
#pragma unroll
    for (int k = 0; k < 6; ++k) {
        int i   = k * 512 + t;
        int c   = i >> 10;         // 1024 float4 per channel
        int rem = i & 1023;
        int hi  = rem >> 2;
        int q   = rem & 3;
        float4 g = *reinterpret_cast<const float4*>(
            base + (size_t)c * NTOT + hi * 256 + lo0 + q * 4);
        float* p = &lds[(c * 256 + hi) * 17 + q * 4];
        p[0] = g.x; p[1] = g.y; p[2] = g.z; p[3] = g.w;
    }
    __syncthreads();

    int lane = t & 63;
    int w    = t >> 6;

    // Each wave owns 6 of the 48 (c,lo) columns; read columns into regs.
    float v[6][4];
#pragma unroll
    for (int u = 0; u < 6; ++u) {
        int idx = w * 6 + u;       // = c*16 + lol
        int c   = idx >> 4;
        int lol = idx & 15;
#pragma unroll
        for (int r = 0; r < 4; ++r)
            v[u][r] = lds[(c * 256 + r * 64 + lane) * 17 + lol];
    }
    __syncthreads();   // all reads done; lds will be overwritten below

    // 256-pt FWHT per column: hi bits 0..5 via shfl, bits 6,7 in-register.
#pragma unroll
    for (int u = 0; u < 6; ++u) {
#pragma unroll
        for (int m = 1; m <= 32; m <<= 1) {
            float p0 = __shfl_xor(v[u][0], m);
            float p1 = __shfl_xor(v[u][1], m);
            float p2 = __shfl_xor(v[u][2], m);
            float p3 = __shfl_xor(v[u][3], m);
            if (lane & m) {
                v[u][0] = p0 - v[u][0]; v[u][1] = p1 - v[u][1];
                v[u][2] = p2 - v[u][2]; v[u][3] = p3 - v[u][3];
            } else {
                v[u][0] += p0; v[u][1] += p1;
                v[u][2] += p2; v[u][3] += p3;
            }
        }
        bfly(v[u][0], v[u][1]); bfly(v[u][2], v[u][3]);   // hi bit 6
        bfly(v[u][0], v[u][2]); bfly(v[u][1], v[u][3]);   // hi bit 7
    }

    // Transpose back: lds2[hi][c*16+lol], stride 49 (odd -> conflict-free).
#pragma unroll
    for (int u = 0; u < 6; ++u) {
        int idx = w * 6 + u;
#pragma unroll
        for (int r = 0; r < 4; ++r)
            lds[(r * 64 + lane) * 49 + idx] = v[u][r];
    }
    __syncthreads();

    // Scatter: n-contiguous iteration -> coalesced jtab/sp reads,
    // one 12B store per live n.
    float* outb = out + (size_t)b * KK;
#pragma unroll
    for (int k = 0; k < 8; ++k) {
        int p  = k * 512 + t;
        int hi = p >> 4;
        int lo = p & 15;
        int n  = hi * 256 + lo0 + lo;
        int j  = jtab[n];
        if (j >= 0) {
            F3 s = *reinterpret_cast<const F3*>(sp + 3 * n);
            float v0 = lds[hi * 49 + lo];
            float v1 = lds[hi * 49 + 16 + lo];
            float v2 = lds[hi * 49 + 32 + lo];
            F3 o;
            o.x = s.x * v0;
            o.y = s.y * v1;
            o.z = s.z * v2;
            *reinterpret_cast<F3*>(outb + 3 * j) = o;
        }
    }
}

extern "C" void kernel_launch(void* const* d_in, const int* in_sizes, int n_in,
                              void* d_out, int out_size, void* d_ws, size_t ws_size,
                              hipStream_t stream) {
    const float* vec  = (const float*)d_in[0];
    const float* sing = (const float*)d_in[1];
    const int*   perm = (const int*)d_in[2];
    float* out = (float*)d_out;

    int*   jtab = (int*)d_ws;                              // 65536 ints  = 256 KB
    float* sp   = (float*)((char*)d_ws + 262144);          // 196608 f32  = 768 KB
    float* mid  = (float*)((char*)d_ws + 1048576);         // B*C*N f32   = 24 MB

    build_tabs_k<<<NTOT / 256, 256, 0, stream>>>(perm, sing, jtab, sp);

    int segs = BB * CCH * (NTOT / 256);                    // 24576 waves
    fwht_lo_k<<<segs / 4, 256, 0, stream>>>(vec, mid);

    fwht_hi_scatter_k<<<BB * 16, 512, 0, stream>>>(mid, jtab, sp, out);
}

// Round 3
// 37.841 us; speedup vs baseline: 1.4988x; 1.0912x over previous
//
#include <hip/hip_runtime.h>

// B=32, C=3, IMG=256, N=65536, K=49152, JMAX=16384
#define NTOT 65536
#define CCH 3
#define BB 32
#define KK 49152
#define JMAXV 16384
#define FWHT_BLOCKS 6144
#define TAB_BLOCKS 256

struct F3 { float x, y, z; };

__device__ __forceinline__ void bfly(float& a, float& b) {
    float s = a + b, d = a - b; a = s; b = d;
}

// masks 1,2: DPP quad_perm (VALU pipe, not LDS)
template<int MASK>
__device__ __forceinline__ float bfly_dpp(float w, int lane) {
    constexpr int ctrl = (MASK == 1) ? 0xB1 : 0x4E;  // [1,0,3,2] / [2,3,0,1]
    float p = __uint_as_float((unsigned)__builtin_amdgcn_update_dpp(
        0, (int)__float_as_uint(w), ctrl, 0xF, 0xF, true));
    return (lane & MASK) ? p - w : w + p;
}

// masks 4,8: ds_swizzle via shfl_xor
template<int MASK>
__device__ __forceinline__ float bfly_swz(float w, int lane) {
    float p = __shfl_xor(w, MASK);
    return (lane & MASK) ? p - w : w + p;
}

// mask 16: permlane16_swap (VALU). r[0]=x[l&~16] (low), r[1]=x[l|16] (high).
__device__ __forceinline__ float bfly_pl16(float w, int lane) {
#if __has_builtin(__builtin_amdgcn_permlane16_swap)
    unsigned u = __float_as_uint(w);
    auto r = __builtin_amdgcn_permlane16_swap(u, u, false, false);
    float a = __uint_as_float(r[0]), b = __uint_as_float(r[1]);
    return (lane & 16) ? a - b : a + b;
#else
    return bfly_swz<16>(w, lane);
#endif
}

// mask 32: permlane32_swap (VALU). r[0]=x[l&31] (low), r[1]=x[l|32] (high).
__device__ __forceinline__ float bfly_pl32(float w, int lane) {
#if __has_builtin(__builtin_amdgcn_permlane32_swap)
    unsigned u = __float_as_uint(w);
    auto r = __builtin_amdgcn_permlane32_swap(u, u, false, false);
    float a = __uint_as_float(r[0]), b = __uint_as_float(r[1]);
    return (lane & 32) ? a - b : a + b;
#else
    return bfly_swz<32>(w, lane);
#endif
}

// 6 lane-exchange butterfly stages (masks 1..32) on 4 values (ILP).
__device__ __forceinline__ void lane_fwht6(float& w0, float& w1, float& w2, float& w3, int lane) {
    w0 = bfly_dpp<1>(w0, lane); w1 = bfly_dpp<1>(w1, lane);
    w2 = bfly_dpp<1>(w2, lane); w3 = bfly_dpp<1>(w3, lane);
    w0 = bfly_dpp<2>(w0, lane); w1 = bfly_dpp<2>(w1, lane);
    w2 = bfly_dpp<2>(w2, lane); w3 = bfly_dpp<2>(w3, lane);
    w0 = bfly_swz<4>(w0, lane); w1 = bfly_swz<4>(w1, lane);
    w2 = bfly_swz<4>(w2, lane); w3 = bfly_swz<4>(w3, lane);
    w0 = bfly_swz<8>(w0, lane); w1 = bfly_swz<8>(w1, lane);
    w2 = bfly_swz<8>(w2, lane); w3 = bfly_swz<8>(w3, lane);
    w0 = bfly_pl16(w0, lane);   w1 = bfly_pl16(w1, lane);
    w2 = bfly_pl16(w2, lane);   w3 = bfly_pl16(w3, lane);
    w0 = bfly_pl32(w0, lane);   w1 = bfly_pl32(w1, lane);
    w2 = bfly_pl32(w2, lane);   w3 = bfly_pl32(w3, lane);
}

__device__ __forceinline__ unsigned short f2bf(float f) {   // round-to-nearest-ish
    return (unsigned short)((__float_as_uint(f) + 0x8000u) >> 16);
}
__device__ __forceinline__ float bf2f(unsigned short b) {
    return __uint_as_float(((unsigned)b) << 16);
}

// K1: lo-FWHT (8 bits) of each contiguous 256-seg, bf16 output; plus the
// table-build blocks fused at the tail of the grid.
__global__ __launch_bounds__(256) void k1_lo_tabs(
        const float* __restrict__ vec, unsigned short* __restrict__ mid,
        const int* __restrict__ perm, const float* __restrict__ sing,
        int* __restrict__ jtab, float* __restrict__ sp) {
    int bx = blockIdx.x, t = threadIdx.x;
    if (bx < FWHT_BLOCKS) {
        int gid  = bx * 256 + t;
        int lane = gid & 63;
        size_t base = (size_t)(gid >> 6) * 256 + lane * 4;
        float4 x = *reinterpret_cast<const float4*>(vec + base);
        float w0 = x.x, w1 = x.y, w2 = x.z, w3 = x.w;
        bfly(w0, w1); bfly(w2, w3);   // lo bit 0
        bfly(w0, w2); bfly(w1, w3);   // lo bit 1
        lane_fwht6(w0, w1, w2, w3, lane);  // lo bits 2..7
        uint2 o;
        o.x = (unsigned)f2bf(w0) | ((unsigned)f2bf(w1) << 16);
        o.y = (unsigned)f2bf(w2) | ((unsigned)f2bf(w3) << 16);
        *reinterpret_cast<uint2*>(mid + base) = o;   // 8B coalesced
    } else {
        int j = (bx - FWHT_BLOCKS) * 256 + t;
        int n = perm[j];
        if (j < JMAXV) {
            jtab[n] = j;
            F3 s = *reinterpret_cast<const F3*>(sing + 3 * j);
            F3 o;
            o.x = s.x * (1.0f / 256.0f);
            o.y = s.y * (1.0f / 256.0f);
            o.z = s.z * (1.0f / 256.0f);
            *reinterpret_cast<F3*>(sp + 3 * n) = o;
        } else {
            jtab[n] = -1;
        }
    }
}

// K2: hi-FWHT (8 bits) on bf16 mid for all 3 channels of one (b, 8-lo) tile,
// then fused scatter out[b][3j+c] = sp[3n+c]*y_c[n], j=jtab[n].
// lds pitch 10 shorts (bank step 5, conflict-free column-pair reads);
// scatter region pitch 26 shorts (bank step 13).
__global__ __launch_bounds__(256) void k2_hi_scatter(
        const unsigned short* __restrict__ mid, const int* __restrict__ jtab,
        const float* __restrict__ sp, float* __restrict__ out) {
    __shared__ unsigned short lds[768 * 10];   // 15360B; scatter reuse needs 256*26=6656
    int tile = blockIdx.x;            // 32 b * 32 lo-groups
    int b    = tile >> 5;
    int lo0  = (tile & 31) * 8;
    const unsigned short* basep = mid + (size_t)b * (CCH * NTOT);
    int t = threadIdx.x;

    // stage: row = c*256+hi, 8 bf16 per row (one uint4), 4x b32 LDS writes
#pragma unroll
    for (int k = 0; k < 3; ++k) {
        int row = k * 256 + t;
        uint4 g = *reinterpret_cast<const uint4*>(basep + (size_t)row * 256 + lo0);
        unsigned short* p = &lds[row * 10];
        *reinterpret_cast<unsigned*>(p + 0) = g.x;
        *reinterpret_cast<unsigned*>(p + 2) = g.y;
        *reinterpret_cast<unsigned*>(p + 4) = g.z;
        *reinterpret_cast<unsigned*>(p + 6) = g.w;
    }
    __syncthreads();

    int lane = t & 63;
    int w    = t >> 6;

    // 6 (c,lo) columns per wave, read as 3 adjacent bf16-pairs per r
    float v[6][4];
#pragma unroll
    for (int pr = 0; pr < 3; ++pr) {
        int idx = w * 6 + pr * 2;     // even; pair never crosses a channel
        int c   = idx >> 3;
        int lol = idx & 7;
#pragma unroll
        for (int r = 0; r < 4; ++r) {
            unsigned pw = *reinterpret_cast<const unsigned*>(
                &lds[(c * 256 + r * 64 + lane) * 10 + lol]);
            v[pr * 2    ][r] = __uint_as_float(pw << 16);          // elem lol
            v[pr * 2 + 1][r] = __uint_as_float(pw & 0xFFFF0000u);  // elem lol+1
        }
    }
    __syncthreads();   // lds about to be reused for the scatter layout

    // hi-FWHT: bits 0..5 = lane stages, bits 6,7 = in-register r
#pragma unroll
    for (int u = 0; u < 6; ++u) {
        lane_fwht6(v[u][0], v[u][1], v[u][2], v[u][3], lane);
        bfly(v[u][0], v[u][1]); bfly(v[u][2], v[u][3]);   // hi bit 6
        bfly(v[u][0], v[u][2]); bfly(v[u][1], v[u][3]);   // hi bit 7
    }

    // transpose back (bf16 pair-packed): lds[hi*26 + idx]
#pragma unroll
    for (int pr = 0; pr < 3; ++pr) {
        int idx = w * 6 + pr * 2;
#pragma unroll
        for (int r = 0; r < 4; ++r) {
            int hi = r * 64 + lane;
            unsigned pw = (unsigned)f2bf(v[pr * 2][r]) |
                          ((unsigned)f2bf(v[pr * 2 + 1][r]) << 16);
            *reinterpret_cast<unsigned*>(&lds[hi * 26 + idx]) = pw;
        }
    }
    __syncthreads();

    // scatter: n-contiguous; one 12B store per live n
    float* outb = out + (size_t)b * KK;
#pragma unroll
    for (int k = 0; k < 8; ++k) {
        int p  = k * 256 + t;
        int hi = p >> 3;
        int lo = p & 7;
        int n  = hi * 256 + lo0 + lo;
        int j  = jtab[n];
        if (j >= 0) {
            F3 s = *reinterpret_cast<const F3*>(sp + 3 * n);
            float v0 = bf2f(lds[hi * 26 + 0  + lo]);
            float v1 = bf2f(lds[hi * 26 + 8  + lo]);
            float v2 = bf2f(lds[hi * 26 + 16 + lo]);
            F3 o;
            o.x = s.x * v0; o.y = s.y * v1; o.z = s.z * v2;
            *reinterpret_cast<F3*>(outb + 3 * j) = o;
        }
    }
}

extern "C" void kernel_launch(void* const* d_in, const int* in_sizes, int n_in,
                              void* d_out, int out_size, void* d_ws, size_t ws_size,
                              hipStream_t stream) {
    const float* vec  = (const float*)d_in[0];
    const float* sing = (const float*)d_in[1];
    const int*   perm = (const int*)d_in[2];
    float* out = (float*)d_out;

    int*            jtab = (int*)d_ws;                                 // 256 KB
    float*          sp   = (float*)((char*)d_ws + 262144);             // 768 KB
    unsigned short* mid  = (unsigned short*)((char*)d_ws + 1048576);   // 12.6 MB bf16

    k1_lo_tabs<<<FWHT_BLOCKS + TAB_BLOCKS, 256, 0, stream>>>(vec, mid, perm, sing, jtab, sp);
    k2_hi_scatter<<<BB * 32, 256, 0, stream>>>(mid, jtab, sp, out);
}